// Round 1
// baseline (68156.372 us; speedup 1.0000x reference)
//
#include <hip/hip_runtime.h>

// Decoder scan: B=32 batch-parallel sequences, T=150 sequential steps.
// Baseline: per-step kernels on the stream (graph capture friendly).

#define BB 32
#define TT 150
#define LL 400
#define FEATD 512
#define RNND 512
#define ATTD 512
#define EMBD 256
#define VOCABD 5000

__device__ __forceinline__ float fsigmoid(float x) {
    return 1.0f / (1.0f + __expf(-x));
}

__device__ __forceinline__ float ftanh(float x) {
    // tanh(x) = 1 - 2/(exp(2x)+1), clamp to avoid inf/inf
    x = fminf(15.0f, fmaxf(-15.0f, x));
    float e = __expf(2.0f * x);
    return 1.0f - 2.0f / (e + 1.0f);
}

// feat_proj[b,l,a] = sum_f features[b,l,f] * W1[f,a]
__global__ void k_feat_proj(const float* __restrict__ features,
                            const float* __restrict__ W1,
                            float* __restrict__ fp) {
    int idx = blockIdx.x * blockDim.x + threadIdx.x;  // B*L*ATT
    int a = idx % ATTD;
    int bl = idx / ATTD;
    const float* f = features + (size_t)bl * FEATD;
    float acc = 0.f;
#pragma unroll 8
    for (int k = 0; k < FEATD; ++k) acc += f[k] * W1[k * ATTD + a];
    fp[idx] = acc;
}

// One thread per (b, j): full GRU cell -> h_out[b,j]
__global__ void k_gru(const float* __restrict__ emb,
                      const int* __restrict__ formula,
                      const float* __restrict__ Wk,    // [EMB+RNN, 3*RNN]
                      const float* __restrict__ Wr,    // [RNN, 3*RNN]
                      const float* __restrict__ bias,  // [2, 3*RNN]
                      const float* __restrict__ h_in,  // [B, RNN]
                      const float* __restrict__ out_in,// [B, RNN] last_out
                      float* __restrict__ h_out,       // [B, RNN]
                      int t) {
    int idx = blockIdx.x * blockDim.x + threadIdx.x;  // B*RNN
    int j = idx % RNND;
    int b = idx / RNND;
    int tok = formula[b * TT + t];
    const float* x = emb + (size_t)tok * EMBD;
    const float* lo = out_in + (size_t)b * RNND;
    const float* st = h_in + (size_t)b * RNND;

    float xz = bias[j];
    float xr = bias[RNND + j];
    float xh = bias[2 * RNND + j];
#pragma unroll 4
    for (int k = 0; k < EMBD; ++k) {
        float v = x[k];
        const float* row = Wk + (size_t)k * 3 * RNND;
        xz += v * row[j];
        xr += v * row[RNND + j];
        xh += v * row[2 * RNND + j];
    }
#pragma unroll 4
    for (int k = 0; k < RNND; ++k) {
        float v = lo[k];
        const float* row = Wk + (size_t)(EMBD + k) * 3 * RNND;
        xz += v * row[j];
        xr += v * row[RNND + j];
        xh += v * row[2 * RNND + j];
    }
    float rz = bias[3 * RNND + j];
    float rr = bias[4 * RNND + j];
    float rh = bias[5 * RNND + j];
#pragma unroll 4
    for (int k = 0; k < RNND; ++k) {
        float v = st[k];
        const float* row = Wr + (size_t)k * 3 * RNND;
        rz += v * row[j];
        rr += v * row[RNND + j];
        rh += v * row[2 * RNND + j];
    }
    float z = fsigmoid(xz + rz);
    float r = fsigmoid(xr + rr);
    float hh = ftanh(xh + r * rh);
    h_out[idx] = z * st[j] + (1.0f - z) * hh;
}

// One block per batch element: q = h@W2, scores, softmax, ctx, out_state.
__global__ void k_attn(const float* __restrict__ fp,       // [B,L,ATT]
                       const float* __restrict__ features, // [B,L,FEAT]
                       const float* __restrict__ W2,       // [RNN,ATT]
                       const float* __restrict__ V,        // [ATT]
                       const float* __restrict__ outW,     // [RNN+FEAT, RNN]
                       const float* __restrict__ h,        // [B,RNN]
                       float* __restrict__ out_state) {    // [B,RNN]
    __shared__ float sh[RNND + FEATD];  // h then ctx
    __shared__ float sq[ATTD];
    __shared__ float sw[LL];
    __shared__ float red[256];
    int b = blockIdx.x;
    int tid = threadIdx.x;

    for (int j = tid; j < RNND; j += 256) sh[j] = h[(size_t)b * RNND + j];
    __syncthreads();

    // q = h @ W2
    for (int a = tid; a < ATTD; a += 256) {
        float acc = 0.f;
#pragma unroll 8
        for (int k = 0; k < RNND; ++k) acc += sh[k] * W2[(size_t)k * ATTD + a];
        sq[a] = acc;
    }
    __syncthreads();

    // scores
    for (int l = tid; l < LL; l += 256) {
        const float* row = fp + ((size_t)b * LL + l) * ATTD;
        float acc = 0.f;
#pragma unroll 8
        for (int a = 0; a < ATTD; ++a) acc += ftanh(row[a] + sq[a]) * V[a];
        sw[l] = acc;
    }
    __syncthreads();

    // softmax over L
    float m = -1e30f;
    for (int l = tid; l < LL; l += 256) m = fmaxf(m, sw[l]);
    red[tid] = m;
    __syncthreads();
    for (int s = 128; s > 0; s >>= 1) {
        if (tid < s) red[tid] = fmaxf(red[tid], red[tid + s]);
        __syncthreads();
    }
    m = red[0];
    __syncthreads();
    float sum = 0.f;
    for (int l = tid; l < LL; l += 256) {
        float e = __expf(sw[l] - m);
        sw[l] = e;
        sum += e;
    }
    red[tid] = sum;
    __syncthreads();
    for (int s = 128; s > 0; s >>= 1) {
        if (tid < s) red[tid] += red[tid + s];
        __syncthreads();
    }
    float inv = 1.0f / red[0];
    __syncthreads();

    // ctx
    for (int f = tid; f < FEATD; f += 256) {
        float acc = 0.f;
#pragma unroll 8
        for (int l = 0; l < LL; ++l)
            acc += sw[l] * features[((size_t)b * LL + l) * FEATD + f];
        sh[RNND + f] = acc * inv;
    }
    __syncthreads();

    // out_state = tanh(concat(h, ctx) @ outW)
    for (int j = tid; j < RNND; j += 256) {
        float acc = 0.f;
#pragma unroll 8
        for (int k = 0; k < RNND + FEATD; ++k) acc += sh[k] * outW[(size_t)k * RNND + j];
        out_state[(size_t)b * RNND + j] = ftanh(acc);
    }
}

// logits[b,t,v] = out_state[b,:] . proj_W[:,v]
__global__ void k_logits(const float* __restrict__ out_state,
                         const float* __restrict__ Wp,  // [RNN, VOCAB]
                         float* __restrict__ logits, int t) {
    int idx = blockIdx.x * blockDim.x + threadIdx.x;  // B*VOCAB
    if (idx >= BB * VOCABD) return;
    int v = idx % VOCABD;
    int b = idx / VOCABD;
    const float* o = out_state + (size_t)b * RNND;
    float acc = 0.f;
#pragma unroll 8
    for (int k = 0; k < RNND; ++k) acc += o[k] * Wp[(size_t)k * VOCABD + v];
    logits[((size_t)b * TT + t) * VOCABD + v] = acc;
}

extern "C" void kernel_launch(void* const* d_in, const int* in_sizes, int n_in,
                              void* d_out, int out_size, void* d_ws, size_t ws_size,
                              hipStream_t stream) {
    const float* features  = (const float*)d_in[0];
    const float* initstate = (const float*)d_in[1];
    const float* emb       = (const float*)d_in[2];
    const float* gruK      = (const float*)d_in[3];
    const float* gruR      = (const float*)d_in[4];
    const float* gruB      = (const float*)d_in[5];
    const float* W1        = (const float*)d_in[6];
    const float* W2        = (const float*)d_in[7];
    const float* V         = (const float*)d_in[8];
    const float* outW      = (const float*)d_in[9];
    const float* projW     = (const float*)d_in[10];
    const int*   formula   = (const int*)d_in[11];
    float* logits = (float*)d_out;

    // workspace layout: feat_proj [B*L*ATT] f32, then h0, h1, out_state
    char* ws = (char*)d_ws;
    float* fp = (float*)ws;
    size_t fp_elems = (size_t)BB * LL * ATTD;
    float* h0   = (float*)(ws + fp_elems * sizeof(float));
    float* h1   = h0 + (size_t)BB * RNND;
    float* outs = h1 + (size_t)BB * RNND;

    hipMemcpyAsync(h0, initstate, (size_t)BB * RNND * sizeof(float),
                   hipMemcpyDeviceToDevice, stream);
    hipMemsetAsync(outs, 0, (size_t)BB * RNND * sizeof(float), stream);

    k_feat_proj<<<(BB * LL * ATTD) / 256, 256, 0, stream>>>(features, W1, fp);

    float* hin = h0;
    float* hout = h1;
    for (int t = 0; t < TT; ++t) {
        k_gru<<<(BB * RNND) / 256, 256, 0, stream>>>(emb, formula, gruK, gruR, gruB,
                                                     hin, outs, hout, t);
        k_attn<<<BB, 256, 0, stream>>>(fp, features, W2, V, outW, hout, outs);
        k_logits<<<(BB * VOCABD + 255) / 256, 256, 0, stream>>>(outs, projW, logits, t);
        float* tmp = hin; hin = hout; hout = tmp;
    }
}

// Round 2
// 19253.276 us; speedup vs baseline: 3.5400x; 3.5400x over previous
//
#include <hip/hip_runtime.h>

#define BB 32
#define TT 150
#define LL 400
#define FEATD 512
#define RNND 512
#define ATTD 512
#define EMBD 256
#define VOCABD 5000

#define G3 (3*RNND)      // 1536
#define KCH 128          // k-chunk for split-K GEMMs
#define MXS 6            // mx k-splits (K=768)
#define MHS 4            // mh k-splits (K=512)
#define OSS 8            // out_state k-splits (K=1024)
#define CTS 4            // ctx l-splits (L=400 -> 100 each)

__device__ __forceinline__ float fsigmoid(float x) {
    return 1.0f / (1.0f + __expf(-x));
}
__device__ __forceinline__ float ftanh(float x) {
    x = fminf(15.0f, fmaxf(-15.0f, x));
    float e = __expf(2.0f * x);
    return 1.0f - 2.0f / (e + 1.0f);
}

// ---------- one-time: feat_proj[b,l,a] = sum_f features[b,l,f] * W1[f,a]
__global__ void k_feat_proj(const float* __restrict__ features,
                            const float* __restrict__ W1,
                            float* __restrict__ fp) {
    int idx = blockIdx.x * blockDim.x + threadIdx.x;  // B*L*ATT
    int a = idx % ATTD;
    int bl = idx / ATTD;
    const float* f = features + (size_t)bl * FEATD;
    float acc = 0.f;
#pragma unroll 8
    for (int k = 0; k < FEATD; ++k) acc += f[k] * W1[(size_t)k * ATTD + a];
    fp[idx] = acc;
}

// ---------- K1: GRU gate GEMM partials (mx and mh), split-K, no atomics.
// mx: inp=[emb(tok) | tanh(sum outpp)] (K=768) @ Wk[768,1536]
// mh: h (K=512) @ Wr[512,1536]
// Block: 64-wide j tile x all 32 b, k-chunk of 128. 240 blocks.
__global__ __launch_bounds__(256) void k_gates(
    const float* __restrict__ emb, const int* __restrict__ formula,
    const float* __restrict__ Wk, const float* __restrict__ Wr,
    const float* __restrict__ h, const float* __restrict__ outpp,
    float* __restrict__ mxp, float* __restrict__ mhp, int t) {
    __shared__ float sk[KCH][BB + 1];
    __shared__ int stok[BB];
    int blk = blockIdx.x, tid = threadIdx.x;
    bool isMX = blk < 24 * MXS;
    int jt, s;
    const float* W;
    float* outbuf;
    if (isMX) { jt = blk % 24; s = blk / 24; W = Wk; outbuf = mxp; }
    else { int r = blk - 24 * MXS; jt = r % 24; s = r / 24; W = Wr; outbuf = mhp; }
    int k0 = s * KCH;

    if (isMX && tid < BB) stok[tid] = formula[tid * TT + t];
    __syncthreads();

    // stage activations [k][b]
    for (int qq = 0; qq < 16; ++qq) {
        int lin = tid + qq * 256;
        int k = lin & (KCH - 1);
        int b = lin >> 7;
        float v;
        if (isMX) {
            int kk = k0 + k;
            if (kk < EMBD) {
                v = emb[(size_t)stok[b] * EMBD + kk];
            } else {
                int kr = kk - EMBD;
                float ps = 0.f;
#pragma unroll
                for (int p = 0; p < OSS; ++p)
                    ps += outpp[((size_t)(p * BB + b)) * RNND + kr];
                v = ftanh(ps);  // last_out = tanh(out_pre)
            }
        } else {
            v = h[(size_t)b * RNND + k0 + k];
        }
        sk[k][b] = v;
    }
    __syncthreads();

    int jl = tid & 63, bq = tid >> 6;
    int j = jt * 64 + jl;
    float acc[8] = {0.f, 0.f, 0.f, 0.f, 0.f, 0.f, 0.f, 0.f};
#pragma unroll 4
    for (int k = 0; k < KCH; ++k) {
        float w = W[(size_t)(k0 + k) * G3 + j];
#pragma unroll
        for (int i = 0; i < 8; ++i) acc[i] += w * sk[k][bq * 8 + i];
    }
#pragma unroll
    for (int i = 0; i < 8; ++i) {
        int b = bq * 8 + i;
        outbuf[((size_t)(s * BB + b)) * G3 + j] = acc[i];
    }
}

// ---------- K2: reduce gate partials -> GRU nonlinearity -> h; then q = h@W2.
// One block per b, 512 threads.
__global__ __launch_bounds__(512) void k_combine_q(
    const float* __restrict__ mxp, const float* __restrict__ mhp,
    const float* __restrict__ bias, const float* __restrict__ W2,
    float* __restrict__ h, float* __restrict__ q) {
    __shared__ float sh[RNND];
    int b = blockIdx.x, j = threadIdx.x;
    float xz = bias[j], xr = bias[RNND + j], xh = bias[2 * RNND + j];
#pragma unroll
    for (int s = 0; s < MXS; ++s) {
        size_t base = ((size_t)(s * BB + b)) * G3;
        xz += mxp[base + j];
        xr += mxp[base + RNND + j];
        xh += mxp[base + 2 * RNND + j];
    }
    float rz = bias[G3 + j], rr = bias[G3 + RNND + j], rh = bias[G3 + 2 * RNND + j];
#pragma unroll
    for (int s = 0; s < MHS; ++s) {
        size_t base = ((size_t)(s * BB + b)) * G3;
        rz += mhp[base + j];
        rr += mhp[base + RNND + j];
        rh += mhp[base + 2 * RNND + j];
    }
    float hp = h[(size_t)b * RNND + j];
    float z = fsigmoid(xz + rz), r = fsigmoid(xr + rr);
    float hh = ftanh(xh + r * rh);
    float hn = z * hp + (1.f - z) * hh;
    h[(size_t)b * RNND + j] = hn;
    sh[j] = hn;
    __syncthreads();
    float acc = 0.f;
#pragma unroll 8
    for (int k = 0; k < RNND; ++k) acc += sh[k] * W2[(size_t)k * ATTD + j];
    q[(size_t)b * ATTD + j] = acc;
}

// ---------- K3: scores. One wave per (b,l): e[b,l] = exp(sum_a tanh(fp+q)*V).
// No max-subtract: |score| <= sum|V| ~ 20, exp safe in fp32. 3200 blocks.
__global__ __launch_bounds__(256) void k_scores(
    const float* __restrict__ fp, const float* __restrict__ q,
    const float* __restrict__ V, float* __restrict__ e) {
    int blk = blockIdx.x;
    int b = blk / 100;
    int wid = threadIdx.x >> 6, lane = threadIdx.x & 63;
    int l = (blk % 100) * 4 + wid;
    const float4* qv = (const float4*)(q + (size_t)b * ATTD);
    float4 q0 = qv[lane], q1 = qv[64 + lane];
    const float4* vv = (const float4*)V;
    float4 v0 = vv[lane], v1 = vv[64 + lane];
    const float4* fr = (const float4*)(fp + ((size_t)b * LL + l) * ATTD);
    float4 f0 = fr[lane], f1 = fr[64 + lane];
    float sacc;
    sacc  = ftanh(f0.x + q0.x) * v0.x + ftanh(f0.y + q0.y) * v0.y
          + ftanh(f0.z + q0.z) * v0.z + ftanh(f0.w + q0.w) * v0.w;
    sacc += ftanh(f1.x + q1.x) * v1.x + ftanh(f1.y + q1.y) * v1.y
          + ftanh(f1.z + q1.z) * v1.z + ftanh(f1.w + q1.w) * v1.w;
#pragma unroll
    for (int o = 32; o > 0; o >>= 1) sacc += __shfl_xor(sacc, o, 64);
    if (lane == 0) e[(size_t)b * LL + l] = __expf(sacc);
}

// ---------- K4: ctx partials over l-chunks + per-(b,ls) e-sums. 256 blocks.
__global__ __launch_bounds__(256) void k_ctx(
    const float* __restrict__ e, const float* __restrict__ features,
    float* __restrict__ ctxp, float* __restrict__ esump) {
    int blk = blockIdx.x;
    int ls = blk & 3, b = (blk >> 2) & 31, fh = blk >> 7;
    int tid = threadIdx.x;
    int f = fh * 256 + tid;
    int l0 = ls * 100;
    float acc = 0.f;
    for (int l = l0; l < l0 + 100; ++l)
        acc += e[(size_t)b * LL + l] * features[((size_t)b * LL + l) * FEATD + f];
    ctxp[((size_t)(ls * BB + b)) * FEATD + f] = acc;
    if (fh == 0) {
        __shared__ float sred[128];
        if (tid < 128) sred[tid] = (tid < 100) ? e[(size_t)b * LL + l0 + tid] : 0.f;
        __syncthreads();
        for (int st = 64; st > 0; st >>= 1) {
            if (tid < st) sred[tid] += sred[tid + st];
            __syncthreads();
        }
        if (tid == 0) esump[ls * BB + b] = sred[0];
    }
}

// ---------- K5: out_state pre-activation partials. cat(h, ctx*inv) @ outW.
// 64 blocks: 8 j-tiles x 8 k-splits.
__global__ __launch_bounds__(256) void k_outstate(
    const float* __restrict__ h, const float* __restrict__ ctxp,
    const float* __restrict__ esump, const float* __restrict__ outW,
    float* __restrict__ outpp) {
    __shared__ float sk[KCH][BB + 1];
    __shared__ float sinv[BB];
    int blk = blockIdx.x, tid = threadIdx.x;
    int jt = blk & 7, s = blk >> 3;
    int k0 = s * KCH;
    if (tid < BB)
        sinv[tid] = 1.f / (esump[tid] + esump[BB + tid] +
                           esump[2 * BB + tid] + esump[3 * BB + tid]);
    __syncthreads();
    for (int qq = 0; qq < 16; ++qq) {
        int lin = tid + qq * 256;
        int k = lin & (KCH - 1), b = lin >> 7;
        int kk = k0 + k;
        float v;
        if (kk < RNND) {
            v = h[(size_t)b * RNND + kk];
        } else {
            int kr = kk - RNND;
            float c = ctxp[((size_t)(0 * BB + b)) * FEATD + kr]
                    + ctxp[((size_t)(1 * BB + b)) * FEATD + kr]
                    + ctxp[((size_t)(2 * BB + b)) * FEATD + kr]
                    + ctxp[((size_t)(3 * BB + b)) * FEATD + kr];
            v = c * sinv[b];
        }
        sk[k][b] = v;
    }
    __syncthreads();
    int jl = tid & 63, bq = tid >> 6;
    int j = jt * 64 + jl;
    float acc[8] = {0.f, 0.f, 0.f, 0.f, 0.f, 0.f, 0.f, 0.f};
#pragma unroll 4
    for (int k = 0; k < KCH; ++k) {
        float w = outW[(size_t)(k0 + k) * RNND + j];
#pragma unroll
        for (int i = 0; i < 8; ++i) acc[i] += w * sk[k][bq * 8 + i];
    }
#pragma unroll
    for (int i = 0; i < 8; ++i)
        outpp[((size_t)(s * BB + bq * 8 + i)) * RNND + j] = acc[i];
}

// ---------- K6: logits. Stage tanh(out_pre) for 4 b in LDS, then GEMM.
// 160 blocks: 8 b-groups x 20 v-tiles. Writes d_out directly.
__global__ __launch_bounds__(256) void k_logits(
    const float* __restrict__ outpp, const float* __restrict__ Wp,
    float* __restrict__ out, int t) {
    __shared__ float so[4][RNND];
    int blk = blockIdx.x, tid = threadIdx.x;
    int vt = blk % 20, bg = blk / 20;
    int v = vt * 256 + tid;
    int b0 = bg * 4;
    for (int qq = 0; qq < 8; ++qq) {
        int lin = tid + qq * 256;
        int k = lin & (RNND - 1), bi = lin >> 9;
        float ps = 0.f;
#pragma unroll
        for (int p = 0; p < OSS; ++p)
            ps += outpp[((size_t)(p * BB + b0 + bi)) * RNND + k];
        so[bi][k] = ftanh(ps);
    }
    __syncthreads();
    if (v < VOCABD) {
        float a0 = 0.f, a1 = 0.f, a2 = 0.f, a3 = 0.f;
#pragma unroll 4
        for (int k = 0; k < RNND; ++k) {
            float w = Wp[(size_t)k * VOCABD + v];
            a0 += w * so[0][k];
            a1 += w * so[1][k];
            a2 += w * so[2][k];
            a3 += w * so[3][k];
        }
        out[((size_t)(b0 + 0) * TT + t) * VOCABD + v] = a0;
        out[((size_t)(b0 + 1) * TT + t) * VOCABD + v] = a1;
        out[((size_t)(b0 + 2) * TT + t) * VOCABD + v] = a2;
        out[((size_t)(b0 + 3) * TT + t) * VOCABD + v] = a3;
    }
}

extern "C" void kernel_launch(void* const* d_in, const int* in_sizes, int n_in,
                              void* d_out, int out_size, void* d_ws, size_t ws_size,
                              hipStream_t stream) {
    const float* features  = (const float*)d_in[0];
    const float* initstate = (const float*)d_in[1];
    const float* emb       = (const float*)d_in[2];
    const float* gruK      = (const float*)d_in[3];
    const float* gruR      = (const float*)d_in[4];
    const float* gruB      = (const float*)d_in[5];
    const float* W1        = (const float*)d_in[6];
    const float* W2        = (const float*)d_in[7];
    const float* V         = (const float*)d_in[8];
    const float* outW      = (const float*)d_in[9];
    const float* projW     = (const float*)d_in[10];
    const int*   formula   = (const int*)d_in[11];
    float* logits = (float*)d_out;

    float* ws = (float*)d_ws;
    float* fp    = ws;                        // 6,553,600
    float* mxp   = fp + (size_t)BB * LL * ATTD;       // 294,912
    float* mhp   = mxp + (size_t)MXS * BB * G3;       // 196,608
    float* h     = mhp + (size_t)MHS * BB * G3;       // 16,384
    float* q     = h + (size_t)BB * RNND;             // 16,384
    float* e     = q + (size_t)BB * ATTD;             // 12,800
    float* esump = e + (size_t)BB * LL;               // 128
    float* ctxp  = esump + CTS * BB;                  // 65,536
    float* outpp = ctxp + (size_t)CTS * BB * FEATD;   // 131,072

    // out_pre partials must be zero so last_out(t=0)=tanh(0)=0; graph replays
    // re-run this memset so state never leaks across calls.
    hipMemsetAsync(outpp, 0, (size_t)OSS * BB * RNND * sizeof(float), stream);
    hipMemcpyAsync(h, initstate, (size_t)BB * RNND * sizeof(float),
                   hipMemcpyDeviceToDevice, stream);

    k_feat_proj<<<(BB * LL * ATTD) / 256, 256, 0, stream>>>(features, W1, fp);

    for (int t = 0; t < TT; ++t) {
        k_gates<<<24 * (MXS + MHS), 256, 0, stream>>>(emb, formula, gruK, gruR,
                                                      h, outpp, mxp, mhp, t);
        k_combine_q<<<BB, 512, 0, stream>>>(mxp, mhp, gruB, W2, h, q);
        k_scores<<<3200, 256, 0, stream>>>(fp, q, V, e);
        k_ctx<<<256, 256, 0, stream>>>(e, features, ctxp, esump);
        k_outstate<<<64, 256, 0, stream>>>(h, ctxp, esump, outW, outpp);
        k_logits<<<160, 256, 0, stream>>>(outpp, projW, logits, t);
    }
}